// Round 2
// baseline (218.665 us; speedup 1.0000x reference)
//
#include <hip/hip_runtime.h>
#include <hip/hip_bf16.h>

#define BB   2
#define CIN  8
#define COUT 16
#define HH   512
#define WW   1024
#define KK   9
#define NPIX (HH*WW)

typedef unsigned int u32;

// fp32 -> bf16 bits, round-nearest-even
__device__ __forceinline__ u32 f2bf(float f) {
  u32 u = __float_as_uint(f);
  return (u + 0x7fffu + ((u >> 16) & 1u)) >> 16;
}
__device__ __forceinline__ float bflo(u32 u) { return __uint_as_float(u << 16); }
__device__ __forceinline__ float bfhi(u32 u) { return __uint_as_float(u & 0xffff0000u); }
__device__ __forceinline__ u32 comp4(uint4 v, int j) {
  return j == 0 ? v.x : j == 1 ? v.y : j == 2 ? v.z : v.w;
}

// x [B][CIN][H][W] fp32  ->  xT [H][W][B][CIN] bf16 (packed as u32 pairs)
__global__ __launch_bounds__(256) void xpose_k(const float* __restrict__ x,
                                               u32* __restrict__ xT) {
  int idx = blockIdx.x * 256 + threadIdx.x;   // pixel = h*WW + w
  if (idx >= NPIX) return;
  #pragma unroll
  for (int b = 0; b < BB; ++b) {
    u32 pk[4];
    #pragma unroll
    for (int j = 0; j < 4; ++j) {
      float f0 = x[(size_t)(b * CIN + 2 * j    ) * NPIX + idx];
      float f1 = x[(size_t)(b * CIN + 2 * j + 1) * NPIX + idx];
      pk[j] = f2bf(f0) | (f2bf(f1) << 16);
    }
    uint4 v; v.x = pk[0]; v.y = pk[1]; v.z = pk[2]; v.w = pk[3];
    ((uint4*)xT)[idx * 2 + b] = v;   // 16B = 8 channels of (pixel, b)
  }
}

// main kernel: one thread per output pixel, both batches, all 16 outputs
__global__ __launch_bounds__(256) void mconv_k(const u32* __restrict__ xT,
                                               const float* __restrict__ sm,
                                               const float* __restrict__ weight,
                                               const float* __restrict__ bias,
                                               float* __restrict__ out) {
  __shared__ float wlds[KK * CIN * COUT];          // [k][c][o]
  int tid = threadIdx.x;
  for (int i = tid; i < KK * CIN * COUT; i += 256) {
    int k = i >> 7, c = (i >> 4) & 7, o = i & 15;
    wlds[i] = weight[(o * CIN + c) * KK + k];
  }
  __syncthreads();

  int p = blockIdx.x * 256 + tid;
  if (p >= NPIX) return;

  float acc[2][COUT];
  #pragma unroll
  for (int o = 0; o < COUT; ++o) { float bv = bias[o]; acc[0][o] = bv; acc[1][o] = bv; }

  const float2* smp = (const float2*)sm;
  const uint4*  xt4 = (const uint4*)xT;

  #pragma unroll 3
  for (int k = 0; k < KK; ++k) {
    float2 s = smp[(size_t)p * KK + k];
    float x0f = floorf(s.x), y0f = floorf(s.y);
    float wx = s.x - x0f, wy = s.y - y0f;
    int x0 = min(max((int)x0f, 0), WW - 1);
    int y0 = min(max((int)y0f, 0), HH - 1);
    int x1 = min(x0 + 1, WW - 1), y1 = min(y0 + 1, HH - 1);
    float w00 = (1.f - wy) * (1.f - wx), w01 = (1.f - wy) * wx;
    float w10 = wy * (1.f - wx),         w11 = wy * wx;

    int b00 = (y0 * WW + x0) * 2, b01 = (y0 * WW + x1) * 2;
    int b10 = (y1 * WW + x0) * 2, b11 = (y1 * WW + x1) * 2;

    uint4 v[2][4];
    #pragma unroll
    for (int b = 0; b < 2; ++b) {
      v[b][0] = xt4[b00 + b]; v[b][1] = xt4[b01 + b];
      v[b][2] = xt4[b10 + b]; v[b][3] = xt4[b11 + b];
    }

    float sv[2][8];
    #pragma unroll
    for (int b = 0; b < 2; ++b) {
      #pragma unroll
      for (int j = 0; j < 4; ++j) {
        u32 u0 = comp4(v[b][0], j), u1 = comp4(v[b][1], j);
        u32 u2 = comp4(v[b][2], j), u3 = comp4(v[b][3], j);
        sv[b][2*j]   = w00*bflo(u0) + w01*bflo(u1) + w10*bflo(u2) + w11*bflo(u3);
        sv[b][2*j+1] = w00*bfhi(u0) + w01*bfhi(u1) + w10*bfhi(u2) + w11*bfhi(u3);
      }
    }

    const float4* w4 = (const float4*)&wlds[k * (CIN * COUT)];
    #pragma unroll
    for (int c = 0; c < 8; ++c) {
      float s0 = sv[0][c], s1 = sv[1][c];
      #pragma unroll
      for (int og = 0; og < 4; ++og) {
        float4 wv = w4[c * 4 + og];
        acc[0][og*4+0] += s0 * wv.x; acc[1][og*4+0] += s1 * wv.x;
        acc[0][og*4+1] += s0 * wv.y; acc[1][og*4+1] += s1 * wv.y;
        acc[0][og*4+2] += s0 * wv.z; acc[1][og*4+2] += s1 * wv.z;
        acc[0][og*4+3] += s0 * wv.w; acc[1][og*4+3] += s1 * wv.w;
      }
    }
  }

  #pragma unroll
  for (int b = 0; b < 2; ++b)
    #pragma unroll
    for (int o = 0; o < COUT; ++o)
      out[(size_t)(b * COUT + o) * NPIX + p] = acc[b][o];
}

// fallback if workspace too small: gather directly from fp32 x [B][C][H][W]
__global__ __launch_bounds__(256) void mconv_direct_k(const float* __restrict__ x,
                                                      const float* __restrict__ sm,
                                                      const float* __restrict__ weight,
                                                      const float* __restrict__ bias,
                                                      float* __restrict__ out) {
  __shared__ float wlds[KK * CIN * COUT];
  int tid = threadIdx.x;
  for (int i = tid; i < KK * CIN * COUT; i += 256) {
    int k = i >> 7, c = (i >> 4) & 7, o = i & 15;
    wlds[i] = weight[(o * CIN + c) * KK + k];
  }
  __syncthreads();

  int p = blockIdx.x * 256 + tid;
  if (p >= NPIX) return;

  float acc[2][COUT];
  #pragma unroll
  for (int o = 0; o < COUT; ++o) { float bv = bias[o]; acc[0][o] = bv; acc[1][o] = bv; }

  const float2* smp = (const float2*)sm;

  for (int k = 0; k < KK; ++k) {
    float2 s = smp[(size_t)p * KK + k];
    float x0f = floorf(s.x), y0f = floorf(s.y);
    float wx = s.x - x0f, wy = s.y - y0f;
    int x0 = min(max((int)x0f, 0), WW - 1);
    int y0 = min(max((int)y0f, 0), HH - 1);
    int x1 = min(x0 + 1, WW - 1), y1 = min(y0 + 1, HH - 1);
    float w00 = (1.f - wy) * (1.f - wx), w01 = (1.f - wy) * wx;
    float w10 = wy * (1.f - wx),         w11 = wy * wx;

    float sv[2][8];
    #pragma unroll
    for (int b = 0; b < 2; ++b) {
      #pragma unroll
      for (int c = 0; c < 8; ++c) {
        const float* xp = x + (size_t)(b * CIN + c) * NPIX;
        float v00 = xp[y0 * WW + x0], v01 = xp[y0 * WW + x1];
        float v10 = xp[y1 * WW + x0], v11 = xp[y1 * WW + x1];
        sv[b][c] = w00 * v00 + w01 * v01 + w10 * v10 + w11 * v11;
      }
    }

    const float4* w4 = (const float4*)&wlds[k * (CIN * COUT)];
    #pragma unroll
    for (int c = 0; c < 8; ++c) {
      float s0 = sv[0][c], s1 = sv[1][c];
      #pragma unroll
      for (int og = 0; og < 4; ++og) {
        float4 wv = w4[c * 4 + og];
        acc[0][og*4+0] += s0 * wv.x; acc[1][og*4+0] += s1 * wv.x;
        acc[0][og*4+1] += s0 * wv.y; acc[1][og*4+1] += s1 * wv.y;
        acc[0][og*4+2] += s0 * wv.z; acc[1][og*4+2] += s1 * wv.z;
        acc[0][og*4+3] += s0 * wv.w; acc[1][og*4+3] += s1 * wv.w;
      }
    }
  }

  #pragma unroll
  for (int b = 0; b < 2; ++b)
    #pragma unroll
    for (int o = 0; o < COUT; ++o)
      out[(size_t)(b * COUT + o) * NPIX + p] = acc[b][o];
}

extern "C" void kernel_launch(void* const* d_in, const int* in_sizes, int n_in,
                              void* d_out, int out_size, void* d_ws, size_t ws_size,
                              hipStream_t stream) {
  const float* x      = (const float*)d_in[0];
  const float* sm     = (const float*)d_in[1];
  const float* weight = (const float*)d_in[2];
  const float* bias   = (const float*)d_in[3];
  float* out = (float*)d_out;

  const size_t need = (size_t)NPIX * (BB * CIN) * sizeof(ushort);  // 16 MB bf16 xT
  if (ws_size >= need) {
    u32* xT = (u32*)d_ws;
    hipLaunchKernelGGL(xpose_k, dim3(NPIX / 256), dim3(256), 0, stream, x, xT);
    hipLaunchKernelGGL(mconv_k, dim3(NPIX / 256), dim3(256), 0, stream,
                       xT, sm, weight, bias, out);
  } else {
    hipLaunchKernelGGL(mconv_direct_k, dim3(NPIX / 256), dim3(256), 0, stream,
                       x, sm, weight, bias, out);
  }
}